// Round 9
// baseline (5533.038 us; speedup 1.0000x reference)
//
#include <hip/hip_runtime.h>
#include <hip/hip_bf16.h>

#define B_  256
#define T_  256
#define F_  64
#define U_  512
#define NG_ 2048   // 4*U
#define BU_ (B_ * U_)

typedef __attribute__((ext_vector_type(8))) short short8;
typedef __attribute__((ext_vector_type(16))) float floatx16;

__device__ __forceinline__ unsigned short f2bf(float f) {
    union { float f; unsigned int u; } v; v.f = f;
    unsigned int u = v.u;
    return (unsigned short)((u + 0x7FFFu + ((u >> 16) & 1u)) >> 16);
}

__global__ void cast_x_kernel(const float* __restrict__ x,
                              unsigned short* __restrict__ xb, int n) {
    int i = blockIdx.x * blockDim.x + threadIdx.x;
    if (i < n) xb[i] = f2bf(x[i]);
}

// Pack weights into 32x32x16 MFMA B-fragments, per unit-group (16 units -> 64
// block-local gate cols = 2 n32 tiles: [i16|f16] [g16|o16]).
__global__ void pack32_kernel(const float* __restrict__ W, const float* __restrict__ Uw,
                              unsigned short* __restrict__ dst, int KT, int KX) {
    long tid = (long)blockIdx.x * blockDim.x + threadIdx.x;
    long total = 32L * 2 * KT * 512;
    if (tid >= total) return;
    int j    = (int)(tid & 7);
    int lane = (int)((tid >> 3) & 63);
    int p512 = (int)(tid >> 9);
    int kt   = p512 % KT;
    int q    = p512 / KT;
    int nt   = q & 1;
    int ug   = q >> 1;
    int c    = nt * 32 + (lane & 31);
    int srcn = (c >> 4) * U_ + ug * 16 + (c & 15);
    int k    = kt * 16 + (lane >> 5) * 8 + j;
    float v  = (k < KX) ? W[(long)k * NG_ + srcn] : Uw[(long)(k - KX) * NG_ + srcn];
    dst[tid] = f2bf(v);
}

// LLC-coherent 16-B load, NON-atomic: batched issue, latencies overlap.
__device__ __forceinline__ short8 llc_load(const unsigned short* p) {
    short8 r;
    asm volatile("global_load_dwordx4 %0, %1, off sc0 sc1" : "=v"(r) : "v"(p));
    return r;
}
#define VMWAIT(N) asm volatile("s_waitcnt vmcnt(" #N ")" ::: "memory")
__device__ __forceinline__ void dep8(short8& x) { asm volatile("" : "+v"(x)); }

#define MFMA32(a, b, c) __builtin_amdgcn_mfma_f32_32x32x16_bf16(a, b, c, 0, 0, 0)

// Intra-layer 4-wave sync via LDS seq counters (no block barrier).
__device__ __forceinline__ void pair_sync(int* sq, int wvl, int t, int lane) {
    asm volatile("s_waitcnt lgkmcnt(0)" ::: "memory");   // zs writes visible
    if (lane == 0)
        __hip_atomic_store(&sq[wvl], t + 1, __ATOMIC_RELAXED, __HIP_MEMORY_SCOPE_WORKGROUP);
    int gd = 0;
    for (;;) {
        bool ok = true;
        if (lane < 4)
            ok = __hip_atomic_load(&sq[lane], __ATOMIC_RELAXED, __HIP_MEMORY_SCOPE_WORKGROUP) >= t + 1;
        if (__ballot(ok) == ~0ull) break;
        if (++gd > (1 << 24)) break;
    }
    __atomic_signal_fence(__ATOMIC_ACQUIRE);
}

// Epilogue for 2 cells (row er, units u0,u0+1): z = sum of 4 wave partials +
// bias -> gates -> c,h. One u32 h-store, own-store drain, per-wave flag.
__device__ __forceinline__ void epi(const float (*z)[2][32][34], const float* bias,
                                    int er, int u0, float* c_, unsigned short* hp,
                                    int lane, int t, int* myflag) {
    unsigned int pk = 0;
    #pragma unroll
    for (int j = 0; j < 2; ++j) {
        int u = u0 + j;
        float zi = bias[u], zf = bias[16 + u], zg = bias[32 + u], zo = bias[48 + u];
        #pragma unroll
        for (int ww = 0; ww < 4; ++ww) {
            zi += z[ww][0][er][u];
            zf += z[ww][0][er][16 + u];
            zg += z[ww][1][er][u];
            zo += z[ww][1][er][16 + u];
        }
        float si = 1.f / (1.f + __expf(-zi));
        float sf = 1.f / (1.f + __expf(-zf));
        float so = 1.f / (1.f + __expf(-zo));
        float gg = zg > 0.f ? zg : 0.f;
        float cn = sf * c_[j] + si * gg;
        c_[j] = cn;
        float hn = so * (cn > 0.f ? cn : 0.f);
        pk |= ((unsigned int)f2bf(hn)) << (16 * j);
    }
    __hip_atomic_store((unsigned int*)hp, pk, __ATOMIC_RELAXED, __HIP_MEMORY_SCOPE_AGENT);
    VMWAIT(0);                                  // own h-store acked at LLC
    __atomic_signal_fence(__ATOMIC_RELEASE);
    if (lane == 0)
        __hip_atomic_store(myflag, t + 1, __ATOMIC_RELAXED, __HIP_MEMORY_SCOPE_AGENT);
}

// Persistent 2-layer LSTM, wave-specialized, barrier-free loop.
// 256 blocks x 512 thr = 1 block/CU (8 waves). Waves 0-3 = L1 (k-split 4-way),
// waves 4-7 = L2. Per-wave flags: f[mo][ug*4+wvl] = t+1 <=> that wave's unit
// slice of h[t] is at LLC. All cross-block traffic relaxed sc1 (LLC coherent);
// zero cache-maintenance ops and zero __syncthreads in the loop.
__global__ __launch_bounds__(512, 2) void lstm_persist(
    const unsigned short* __restrict__ xb,
    const unsigned short* __restrict__ P1,
    const unsigned short* __restrict__ P2,
    const float* __restrict__ b1, const float* __restrict__ b2,
    unsigned short* __restrict__ h1r, unsigned short* __restrict__ h2r,
    int* flags1, int* flags2)
{
    const int bid  = blockIdx.x;
    const int mo   = bid & 7;        // m-octile == XCD (locality heuristic)
    const int ug   = bid >> 3;       // 32 unit-groups of 16 units
    const int tid  = threadIdx.x;
    const int w    = tid >> 6;       // 0..7
    const int lane = tid & 63;
    const int arow = lane & 31;
    const int koff = (lane >> 5) * 8;
    const int row  = mo * 32 + arow;

    int* f1 = flags1 + mo * 128;
    int* f2 = flags2 + mo * 128;

    __shared__ float zs[2][2][4][2][32][34];   // [ly][slot][ww][nt][m][n+pad] 136KB
    __shared__ float bias_s[2][64];
    __shared__ int   seqs[2][4];

    if (tid < 8) seqs[tid >> 2][tid & 3] = 0;
    if (tid < 128) {
        int ly = tid >> 6, idx = tid & 63;
        const float* bb = ly ? b2 : b1;
        bias_s[ly][idx] = bb[(idx >> 4) * U_ + ug * 16 + (idx & 15)];
    }
    __syncthreads();   // init only; no barriers in the t-loop

    if (w < 4) {
        // ======================= LAYER 1 (waves 0-3) =======================
        const int wvl = w;
        short8 wf0[9], wf1[9];
        {
            const unsigned short* b0 = P1 + (size_t)ug * (2 * 36 * 512);
            #pragma unroll
            for (int i = 0; i < 9; ++i) {
                wf0[i] = *(const short8*)(b0 + (size_t)(0 * 36 + wvl * 9 + i) * 512 + lane * 8);
                wf1[i] = *(const short8*)(b0 + (size_t)(1 * 36 + wvl * 9 + i) * 512 + lane * 8);
            }
        }
        float c_[2] = {0.f, 0.f};
        const int er = arow;
        const int u0 = wvl * 4 + (lane >> 5) * 2;
        int* myflag = f1 + ug * 4 + wvl;
        const int* pa = f1 + lane;
        const int* pb = f1 + 64 + lane;
        const int* pc = f2 + (lane >> 1) * 4 + (lane & 1);  // L2 waves 0,1 flags

        for (int t = 0; t < T_; ++t) {
            if (t > 0) {                     // h1[t-1] ready + ring backpressure
                const int bp = t - 3;
                int gd = 0;
                for (;;) {
                    bool ok = __hip_atomic_load(pa, __ATOMIC_RELAXED, __HIP_MEMORY_SCOPE_AGENT) >= t
                           && __hip_atomic_load(pb, __ATOMIC_RELAXED, __HIP_MEMORY_SCOPE_AGENT) >= t;
                    if (bp > 0)
                        ok = ok && __hip_atomic_load(pc, __ATOMIC_RELAXED, __HIP_MEMORY_SCOPE_AGENT) >= bp;
                    if (__ballot(ok) == ~0ull) break;
                    __builtin_amdgcn_s_sleep(1);
                    if (++gd > (1 << 21)) break;
                }
            }
            __atomic_signal_fence(__ATOMIC_ACQUIRE);

            floatx16 acc0, acc1;
            #pragma unroll
            for (int i = 0; i < 16; ++i) { acc0[i] = 0.f; acc1[i] = 0.f; }

            short8 fr[9];
            int nf = 0;
            if (wvl == 0) {
                const unsigned short* xbase = xb + ((size_t)row * T_ + t) * F_;
                #pragma unroll
                for (int i = 0; i < 4; ++i) fr[i] = *(const short8*)(xbase + i * 16 + koff);
                if (t > 0) {
                    const unsigned short* hb = h1r + (size_t)((t - 1) & 3) * BU_ + (size_t)row * U_;
                    #pragma unroll
                    for (int i = 4; i < 9; ++i) fr[i] = llc_load(hb + (i - 4) * 16 + koff);
                    nf = 9;
                } else nf = 4;
            } else if (t > 0) {
                const unsigned short* hb = h1r + (size_t)((t - 1) & 3) * BU_ + (size_t)row * U_
                                           + (wvl * 9 - 4) * 16;
                #pragma unroll
                for (int i = 0; i < 9; ++i) fr[i] = llc_load(hb + i * 16 + koff);
                nf = 9;
            }
            if (nf == 9) {
                VMWAIT(0);
                #pragma unroll
                for (int i = 0; i < 9; ++i) {
                    dep8(fr[i]);
                    acc0 = MFMA32(fr[i], wf0[i], acc0);
                    acc1 = MFMA32(fr[i], wf1[i], acc1);
                }
            } else if (nf == 4) {
                VMWAIT(0);
                #pragma unroll
                for (int i = 0; i < 4; ++i) {
                    dep8(fr[i]);
                    acc0 = MFMA32(fr[i], wf0[i], acc0);
                    acc1 = MFMA32(fr[i], wf1[i], acc1);
                }
            }

            const int slot = t & 1;
            #pragma unroll
            for (int r = 0; r < 16; ++r) {   // D: col=lane&31, row=(r&3)+8*(r>>2)+4*(lane>>5)
                int rr = (r & 3) + 8 * (r >> 2) + 4 * (lane >> 5);
                zs[0][slot][wvl][0][rr][arow] = acc0[r];
                zs[0][slot][wvl][1][rr][arow] = acc1[r];
            }
            pair_sync(&seqs[0][0], wvl, t, lane);

            unsigned short* hp = h1r + (size_t)(t & 3) * BU_
                                 + (size_t)(mo * 32 + er) * U_ + ug * 16 + u0;
            epi(zs[0][slot], bias_s[0], er, u0, c_, hp, lane, t, myflag);
        }
    } else {
        // ======================= LAYER 2 (waves 4-7) =======================
        const int wvl = w - 4;               // 0,1 = W2*h1[t]; 2,3 = U2*h2[t-1]
        short8 wf0[16], wf1[16];
        {
            const unsigned short* b0 = P2 + (size_t)ug * (2 * 64 * 512);
            #pragma unroll
            for (int i = 0; i < 16; ++i) {
                int kt = wvl * 16 + i;
                wf0[i] = *(const short8*)(b0 + (size_t)(0 * 64 + kt) * 512 + lane * 8);
                wf1[i] = *(const short8*)(b0 + (size_t)(1 * 64 + kt) * 512 + lane * 8);
            }
        }
        float c_[2] = {0.f, 0.f};
        const int er = arow;
        const int u0 = wvl * 4 + (lane >> 5) * 2;
        int* myflag = f2 + ug * 4 + wvl;
        const int* pa = (wvl < 2) ? (f1 + lane) : (f2 + lane);
        const int* pb = (wvl < 2) ? (f1 + 64 + lane) : (f2 + 64 + lane);

        for (int t = 0; t < T_; ++t) {
            const int tgt = (wvl < 2) ? (t + 1) : t;   // f1>=t+1 or f2>=t
            if (tgt > 0) {
                int gd = 0;
                for (;;) {
                    bool ok = __hip_atomic_load(pa, __ATOMIC_RELAXED, __HIP_MEMORY_SCOPE_AGENT) >= tgt
                           && __hip_atomic_load(pb, __ATOMIC_RELAXED, __HIP_MEMORY_SCOPE_AGENT) >= tgt;
                    if (__ballot(ok) == ~0ull) break;
                    __builtin_amdgcn_s_sleep(1);
                    if (++gd > (1 << 21)) break;
                }
            }
            __atomic_signal_fence(__ATOMIC_ACQUIRE);

            floatx16 acc0, acc1;
            #pragma unroll
            for (int i = 0; i < 16; ++i) { acc0[i] = 0.f; acc1[i] = 0.f; }

            bool have = false;
            short8 fr[16];
            if (wvl < 2) {
                const unsigned short* hb = h1r + (size_t)(t & 3) * BU_ + (size_t)row * U_
                                           + wvl * 256;
                #pragma unroll
                for (int i = 0; i < 16; ++i) fr[i] = llc_load(hb + i * 16 + koff);
                have = true;
            } else if (t > 0) {
                const unsigned short* hb = h2r + (size_t)((t - 1) & 3) * BU_ + (size_t)row * U_
                                           + (wvl - 2) * 256;
                #pragma unroll
                for (int i = 0; i < 16; ++i) fr[i] = llc_load(hb + i * 16 + koff);
                have = true;
            }
            if (have) {
                VMWAIT(0);
                #pragma unroll
                for (int i = 0; i < 16; ++i) {
                    dep8(fr[i]);
                    acc0 = MFMA32(fr[i], wf0[i], acc0);
                    acc1 = MFMA32(fr[i], wf1[i], acc1);
                }
            }

            const int slot = t & 1;
            #pragma unroll
            for (int r = 0; r < 16; ++r) {
                int rr = (r & 3) + 8 * (r >> 2) + 4 * (lane >> 5);
                zs[1][slot][wvl][0][rr][arow] = acc0[r];
                zs[1][slot][wvl][1][rr][arow] = acc1[r];
            }
            pair_sync(&seqs[1][0], wvl, t, lane);

            unsigned short* hp = h2r + (size_t)(t & 3) * BU_
                                 + (size_t)(mo * 32 + er) * U_ + ug * 16 + u0;
            epi(zs[1][slot], bias_s[1], er, u0, c_, hp, lane, t, myflag);
        }
    }
}

__global__ void dense_kernel(const unsigned short* __restrict__ h2,
                             const float* __restrict__ Wd,
                             const float* __restrict__ bd,
                             float* __restrict__ out) {
    int b = blockIdx.x;
    int lane = threadIdx.x;                  // 64 lanes
    const unsigned short* hp = h2 + (long)b * U_ + lane * 8;
    float sum = 0.f;
    #pragma unroll
    for (int j = 0; j < 8; ++j) {
        union { unsigned int u; float f; } v; v.u = ((unsigned int)hp[j]) << 16;
        sum += v.f * Wd[lane * 8 + j];
    }
    #pragma unroll
    for (int off = 32; off; off >>= 1) sum += __shfl_down(sum, off);
    if (lane == 0) out[b] = 1.f / (1.f + __expf(-(sum + bd[0])));
}

extern "C" void kernel_launch(void* const* d_in, const int* in_sizes, int n_in,
                              void* d_out, int out_size, void* d_ws, size_t ws_size,
                              hipStream_t stream) {
    const float* x  = (const float*)d_in[0];
    const float* W1 = (const float*)d_in[1];
    const float* U1 = (const float*)d_in[2];
    const float* b1 = (const float*)d_in[3];
    const float* W2 = (const float*)d_in[4];
    const float* U2 = (const float*)d_in[5];
    const float* b2 = (const float*)d_in[6];
    const float* Wd = (const float*)d_in[7];
    const float* bd = (const float*)d_in[8];
    float* out = (float*)d_out;

    char* ws = (char*)d_ws;
    size_t off = 0;
    unsigned short* xb  = (unsigned short*)(ws + off); off += (size_t)B_ * T_ * F_ * 2;      // 8.39 MB
    unsigned short* P1  = (unsigned short*)(ws + off); off += (size_t)32 * 2 * 36 * 512 * 2; // 2.36 MB
    unsigned short* P2  = (unsigned short*)(ws + off); off += (size_t)32 * 2 * 64 * 512 * 2; // 4.19 MB
    unsigned short* h1r = (unsigned short*)(ws + off); off += (size_t)4 * BU_ * 2;           // 1 MB
    unsigned short* h2r = (unsigned short*)(ws + off); off += (size_t)4 * BU_ * 2;           // 1 MB
    int* flags1 = (int*)(ws + off); off += (size_t)8 * 128 * 4;   // per-wave flags
    int* flags2 = (int*)(ws + off); off += (size_t)8 * 128 * 4;

    hipMemsetAsync(flags1, 0, (size_t)8 * 128 * 4 * 2, stream);

    int n = B_ * T_ * F_;
    cast_x_kernel<<<(n + 255) / 256, 256, 0, stream>>>(x, xb, n);
    {
        long tot1 = 32L * 2 * 36 * 512;
        pack32_kernel<<<(int)((tot1 + 255) / 256), 256, 0, stream>>>(W1, U1, P1, 36, 64);
        long tot2 = 32L * 2 * 64 * 512;
        pack32_kernel<<<(int)((tot2 + 255) / 256), 256, 0, stream>>>(W2, U2, P2, 64, 512);
    }

    // 256 blocks x 512 thr = 1 block/CU (8 waves): co-residency guaranteed.
    lstm_persist<<<256, 512, 0, stream>>>(xb, P1, P2, b1, b2, h1r, h2r, flags1, flags2);

    dense_kernel<<<B_, 64, 0, stream>>>(h2r + (size_t)((T_ - 1) & 3) * BU_,
                                        Wd, bd, out);
}

// Round 10
// 5522.595 us; speedup vs baseline: 1.0019x; 1.0019x over previous
//
#include <hip/hip_runtime.h>
#include <hip/hip_bf16.h>

#define B_  256
#define T_  256
#define F_  64
#define U_  512
#define NG_ 2048   // 4*U
#define BU_ (B_ * U_)

typedef __attribute__((ext_vector_type(8))) short short8;
typedef __attribute__((ext_vector_type(16))) float floatx16;

__device__ __forceinline__ unsigned short f2bf(float f) {
    union { float f; unsigned int u; } v; v.f = f;
    unsigned int u = v.u;
    return (unsigned short)((u + 0x7FFFu + ((u >> 16) & 1u)) >> 16);
}

__global__ void cast_x_kernel(const float* __restrict__ x,
                              unsigned short* __restrict__ xb, int n) {
    int i = blockIdx.x * blockDim.x + threadIdx.x;
    if (i < n) xb[i] = f2bf(x[i]);
}

// Pack weights into 32x32x16 MFMA B-fragments, per unit-group (16 units -> 64
// block-local gate cols = 2 n32 tiles: [i16|f16] [g16|o16]).
__global__ void pack32_kernel(const float* __restrict__ W, const float* __restrict__ Uw,
                              unsigned short* __restrict__ dst, int KT, int KX) {
    long tid = (long)blockIdx.x * blockDim.x + threadIdx.x;
    long total = 32L * 2 * KT * 512;
    if (tid >= total) return;
    int j    = (int)(tid & 7);
    int lane = (int)((tid >> 3) & 63);
    int p512 = (int)(tid >> 9);
    int kt   = p512 % KT;
    int q    = p512 / KT;
    int nt   = q & 1;
    int ug   = q >> 1;
    int c    = nt * 32 + (lane & 31);
    int srcn = (c >> 4) * U_ + ug * 16 + (c & 15);
    int k    = kt * 16 + (lane >> 5) * 8 + j;
    float v  = (k < KX) ? W[(long)k * NG_ + srcn] : Uw[(long)(k - KX) * NG_ + srcn];
    dst[tid] = f2bf(v);
}

// LLC-coherent 16-B load, NON-atomic: batched issue, latencies overlap.
__device__ __forceinline__ short8 llc_load(const unsigned short* p) {
    short8 r;
    asm volatile("global_load_dwordx4 %0, %1, off sc0 sc1" : "=v"(r) : "v"(p));
    return r;
}
#define VMWAIT(N) asm volatile("s_waitcnt vmcnt(" #N ")" ::: "memory")
__device__ __forceinline__ void dep8(short8& x) { asm volatile("" : "+v"(x)); }

#define MFMA32(a, b, c) __builtin_amdgcn_mfma_f32_32x32x16_bf16(a, b, c, 0, 0, 0)

// Intra-layer 4-wave sync via LDS seq counters (no block barrier).
__device__ __forceinline__ void pair_sync(int* sq, int wvl, int t, int lane) {
    asm volatile("s_waitcnt lgkmcnt(0)" ::: "memory");   // zs writes visible
    if (lane == 0)
        __hip_atomic_store(&sq[wvl], t + 1, __ATOMIC_RELAXED, __HIP_MEMORY_SCOPE_WORKGROUP);
    int gd = 0;
    for (;;) {
        bool ok = true;
        if (lane < 4)
            ok = __hip_atomic_load(&sq[lane], __ATOMIC_RELAXED, __HIP_MEMORY_SCOPE_WORKGROUP) >= t + 1;
        if (__ballot(ok) == ~0ull) break;
        if (++gd > (1 << 24)) break;
    }
    __atomic_signal_fence(__ATOMIC_ACQUIRE);
}

// Epilogue for 2 cells (row er, units u0,u0+1): z = sum of 4 wave partials +
// bias -> gates -> c,h. One u32 h-store, own-store drain, per-wave flag.
__device__ __forceinline__ void epi(const float (*z)[2][32][34], const float* bias,
                                    int er, int u0, float* c_, unsigned short* hp,
                                    int lane, int t, int* myflag) {
    unsigned int pk = 0;
    #pragma unroll
    for (int j = 0; j < 2; ++j) {
        int u = u0 + j;
        float zi = bias[u], zf = bias[16 + u], zg = bias[32 + u], zo = bias[48 + u];
        #pragma unroll
        for (int ww = 0; ww < 4; ++ww) {
            zi += z[ww][0][er][u];
            zf += z[ww][0][er][16 + u];
            zg += z[ww][1][er][u];
            zo += z[ww][1][er][16 + u];
        }
        float si = 1.f / (1.f + __expf(-zi));
        float sf = 1.f / (1.f + __expf(-zf));
        float so = 1.f / (1.f + __expf(-zo));
        float gg = zg > 0.f ? zg : 0.f;
        float cn = sf * c_[j] + si * gg;
        c_[j] = cn;
        float hn = so * (cn > 0.f ? cn : 0.f);
        pk |= ((unsigned int)f2bf(hn)) << (16 * j);
    }
    __hip_atomic_store((unsigned int*)hp, pk, __ATOMIC_RELAXED, __HIP_MEMORY_SCOPE_AGENT);
    VMWAIT(0);                                  // own h-store acked at LLC
    __atomic_signal_fence(__ATOMIC_RELEASE);
    if (lane == 0)
        __hip_atomic_store(myflag, t + 1, __ATOMIC_RELAXED, __HIP_MEMORY_SCOPE_AGENT);
}

// Persistent 2-layer LSTM, wave-specialized, barrier-free loop.
// 256 blocks x 512 thr = 1 block/CU (8 waves, 2/SIMD). Waves 0-3 = L1
// (k-split 4-way), waves 4-7 = L2. Per-wave flags; ring depth 8.
// __launch_bounds__(512,1): 1 wave/EU min -> 256-VGPR budget (r9's (512,2)
// meant 4 waves/EU -> 124 VGPRs -> scratch spill; that was the regression).
__global__ __launch_bounds__(512, 1) void lstm_persist(
    const unsigned short* __restrict__ xb,
    const unsigned short* __restrict__ P1,
    const unsigned short* __restrict__ P2,
    const float* __restrict__ b1, const float* __restrict__ b2,
    unsigned short* __restrict__ h1r, unsigned short* __restrict__ h2r,
    int* flags1, int* flags2)
{
    const int bid  = blockIdx.x;
    const int mo   = bid & 7;        // m-octile == XCD (locality heuristic)
    const int ug   = bid >> 3;       // 32 unit-groups of 16 units
    const int tid  = threadIdx.x;
    const int w    = tid >> 6;       // 0..7
    const int lane = tid & 63;
    const int arow = lane & 31;
    const int koff = (lane >> 5) * 8;
    const int row  = mo * 32 + arow;

    int* f1 = flags1 + mo * 128;
    int* f2 = flags2 + mo * 128;

    __shared__ float zs[2][2][4][2][32][34];   // [ly][slot][ww][nt][m][n+pad] 136KB
    __shared__ float bias_s[2][64];
    __shared__ int   seqs[2][4];

    if (tid < 8) seqs[tid >> 2][tid & 3] = 0;
    if (tid < 128) {
        int ly = tid >> 6, idx = tid & 63;
        const float* bb = ly ? b2 : b1;
        bias_s[ly][idx] = bb[(idx >> 4) * U_ + ug * 16 + (idx & 15)];
    }
    __syncthreads();   // init only; no barriers in the t-loop

    if (w < 4) {
        // ======================= LAYER 1 (waves 0-3) =======================
        const int wvl = w;
        short8 wf0[9], wf1[9];
        {
            const unsigned short* b0 = P1 + (size_t)ug * (2 * 36 * 512);
            #pragma unroll
            for (int i = 0; i < 9; ++i) {
                wf0[i] = *(const short8*)(b0 + (size_t)(0 * 36 + wvl * 9 + i) * 512 + lane * 8);
                wf1[i] = *(const short8*)(b0 + (size_t)(1 * 36 + wvl * 9 + i) * 512 + lane * 8);
            }
        }
        float c_[2] = {0.f, 0.f};
        const int er = arow;
        const int u0 = wvl * 4 + (lane >> 5) * 2;
        int* myflag = f1 + ug * 4 + wvl;
        const int* pa  = f1 + lane;
        const int* pb  = f1 + 64 + lane;
        const int* pc1 = f2 + lane;        // backpressure: ALL 128 L2 flags
        const int* pc2 = f2 + 64 + lane;

        for (int t = 0; t < T_; ++t) {
            if (t > 0) {                   // h1[t-1] ready + ring backpressure
                const int bp = t - 6;
                int gd = 0;
                for (;;) {
                    bool ok = __hip_atomic_load(pa, __ATOMIC_RELAXED, __HIP_MEMORY_SCOPE_AGENT) >= t
                           && __hip_atomic_load(pb, __ATOMIC_RELAXED, __HIP_MEMORY_SCOPE_AGENT) >= t;
                    if (bp > 0)
                        ok = ok && __hip_atomic_load(pc1, __ATOMIC_RELAXED, __HIP_MEMORY_SCOPE_AGENT) >= bp
                                && __hip_atomic_load(pc2, __ATOMIC_RELAXED, __HIP_MEMORY_SCOPE_AGENT) >= bp;
                    if (__ballot(ok) == ~0ull) break;
                    __builtin_amdgcn_s_sleep(1);
                    if (++gd > (1 << 21)) break;
                }
            }
            __atomic_signal_fence(__ATOMIC_ACQUIRE);

            floatx16 acc0, acc1;
            #pragma unroll
            for (int i = 0; i < 16; ++i) { acc0[i] = 0.f; acc1[i] = 0.f; }

            short8 fr[9];
            int nf = 0;
            if (wvl == 0) {
                const unsigned short* xbase = xb + ((size_t)row * T_ + t) * F_;
                #pragma unroll
                for (int i = 0; i < 4; ++i) fr[i] = *(const short8*)(xbase + i * 16 + koff);
                if (t > 0) {
                    const unsigned short* hb = h1r + (size_t)((t - 1) & 7) * BU_ + (size_t)row * U_;
                    #pragma unroll
                    for (int i = 4; i < 9; ++i) fr[i] = llc_load(hb + (i - 4) * 16 + koff);
                    nf = 9;
                } else nf = 4;
            } else if (t > 0) {
                const unsigned short* hb = h1r + (size_t)((t - 1) & 7) * BU_ + (size_t)row * U_
                                           + (wvl * 9 - 4) * 16;
                #pragma unroll
                for (int i = 0; i < 9; ++i) fr[i] = llc_load(hb + i * 16 + koff);
                nf = 9;
            }
            if (nf == 9) {
                VMWAIT(0);
                #pragma unroll
                for (int i = 0; i < 9; ++i) {
                    dep8(fr[i]);
                    acc0 = MFMA32(fr[i], wf0[i], acc0);
                    acc1 = MFMA32(fr[i], wf1[i], acc1);
                }
            } else if (nf == 4) {
                VMWAIT(0);
                #pragma unroll
                for (int i = 0; i < 4; ++i) {
                    dep8(fr[i]);
                    acc0 = MFMA32(fr[i], wf0[i], acc0);
                    acc1 = MFMA32(fr[i], wf1[i], acc1);
                }
            }

            const int slot = t & 1;
            #pragma unroll
            for (int r = 0; r < 16; ++r) {   // D: col=lane&31, row=(r&3)+8*(r>>2)+4*(lane>>5)
                int rr = (r & 3) + 8 * (r >> 2) + 4 * (lane >> 5);
                zs[0][slot][wvl][0][rr][arow] = acc0[r];
                zs[0][slot][wvl][1][rr][arow] = acc1[r];
            }
            pair_sync(&seqs[0][0], wvl, t, lane);

            unsigned short* hp = h1r + (size_t)(t & 7) * BU_
                                 + (size_t)(mo * 32 + er) * U_ + ug * 16 + u0;
            epi(zs[0][slot], bias_s[0], er, u0, c_, hp, lane, t, myflag);
        }
    } else {
        // ======================= LAYER 2 (waves 4-7) =======================
        const int wvl = w - 4;               // 0,1 = W2*h1[t]; 2,3 = U2*h2[t-1]
        short8 wf0[16], wf1[16];
        {
            const unsigned short* b0 = P2 + (size_t)ug * (2 * 64 * 512);
            #pragma unroll
            for (int i = 0; i < 16; ++i) {
                int kt = wvl * 16 + i;
                wf0[i] = *(const short8*)(b0 + (size_t)(0 * 64 + kt) * 512 + lane * 8);
                wf1[i] = *(const short8*)(b0 + (size_t)(1 * 64 + kt) * 512 + lane * 8);
            }
        }
        float c_[2] = {0.f, 0.f};
        const int er = arow;
        const int u0 = wvl * 4 + (lane >> 5) * 2;
        int* myflag = f2 + ug * 4 + wvl;
        const int* pa = (wvl < 2) ? (f1 + lane) : (f2 + lane);
        const int* pb = (wvl < 2) ? (f1 + 64 + lane) : (f2 + 64 + lane);

        for (int t = 0; t < T_; ++t) {
            const int tgt = (wvl < 2) ? (t + 1) : t;   // f1>=t+1 or f2>=t
            if (tgt > 0) {
                int gd = 0;
                for (;;) {
                    bool ok = __hip_atomic_load(pa, __ATOMIC_RELAXED, __HIP_MEMORY_SCOPE_AGENT) >= tgt
                           && __hip_atomic_load(pb, __ATOMIC_RELAXED, __HIP_MEMORY_SCOPE_AGENT) >= tgt;
                    if (__ballot(ok) == ~0ull) break;
                    __builtin_amdgcn_s_sleep(1);
                    if (++gd > (1 << 21)) break;
                }
            }
            __atomic_signal_fence(__ATOMIC_ACQUIRE);

            floatx16 acc0, acc1;
            #pragma unroll
            for (int i = 0; i < 16; ++i) { acc0[i] = 0.f; acc1[i] = 0.f; }

            bool have = false;
            short8 fr[16];
            if (wvl < 2) {
                const unsigned short* hb = h1r + (size_t)(t & 7) * BU_ + (size_t)row * U_
                                           + wvl * 256;
                #pragma unroll
                for (int i = 0; i < 16; ++i) fr[i] = llc_load(hb + i * 16 + koff);
                have = true;
            } else if (t > 0) {
                const unsigned short* hb = h2r + (size_t)((t - 1) & 7) * BU_ + (size_t)row * U_
                                           + (wvl - 2) * 256;
                #pragma unroll
                for (int i = 0; i < 16; ++i) fr[i] = llc_load(hb + i * 16 + koff);
                have = true;
            }
            if (have) {
                VMWAIT(0);
                #pragma unroll
                for (int i = 0; i < 16; ++i) {
                    dep8(fr[i]);
                    acc0 = MFMA32(fr[i], wf0[i], acc0);
                    acc1 = MFMA32(fr[i], wf1[i], acc1);
                }
            }

            const int slot = t & 1;
            #pragma unroll
            for (int r = 0; r < 16; ++r) {
                int rr = (r & 3) + 8 * (r >> 2) + 4 * (lane >> 5);
                zs[1][slot][wvl][0][rr][arow] = acc0[r];
                zs[1][slot][wvl][1][rr][arow] = acc1[r];
            }
            pair_sync(&seqs[1][0], wvl, t, lane);

            unsigned short* hp = h2r + (size_t)(t & 7) * BU_
                                 + (size_t)(mo * 32 + er) * U_ + ug * 16 + u0;
            epi(zs[1][slot], bias_s[1], er, u0, c_, hp, lane, t, myflag);
        }
    }
}

__global__ void dense_kernel(const unsigned short* __restrict__ h2,
                             const float* __restrict__ Wd,
                             const float* __restrict__ bd,
                             float* __restrict__ out) {
    int b = blockIdx.x;
    int lane = threadIdx.x;                  // 64 lanes
    const unsigned short* hp = h2 + (long)b * U_ + lane * 8;
    float sum = 0.f;
    #pragma unroll
    for (int j = 0; j < 8; ++j) {
        union { unsigned int u; float f; } v; v.u = ((unsigned int)hp[j]) << 16;
        sum += v.f * Wd[lane * 8 + j];
    }
    #pragma unroll
    for (int off = 32; off; off >>= 1) sum += __shfl_down(sum, off);
    if (lane == 0) out[b] = 1.f / (1.f + __expf(-(sum + bd[0])));
}

extern "C" void kernel_launch(void* const* d_in, const int* in_sizes, int n_in,
                              void* d_out, int out_size, void* d_ws, size_t ws_size,
                              hipStream_t stream) {
    const float* x  = (const float*)d_in[0];
    const float* W1 = (const float*)d_in[1];
    const float* U1 = (const float*)d_in[2];
    const float* b1 = (const float*)d_in[3];
    const float* W2 = (const float*)d_in[4];
    const float* U2 = (const float*)d_in[5];
    const float* b2 = (const float*)d_in[6];
    const float* Wd = (const float*)d_in[7];
    const float* bd = (const float*)d_in[8];
    float* out = (float*)d_out;

    char* ws = (char*)d_ws;
    size_t off = 0;
    unsigned short* xb  = (unsigned short*)(ws + off); off += (size_t)B_ * T_ * F_ * 2;      // 8.39 MB
    unsigned short* P1  = (unsigned short*)(ws + off); off += (size_t)32 * 2 * 36 * 512 * 2; // 2.36 MB
    unsigned short* P2  = (unsigned short*)(ws + off); off += (size_t)32 * 2 * 64 * 512 * 2; // 4.19 MB
    unsigned short* h1r = (unsigned short*)(ws + off); off += (size_t)8 * BU_ * 2;           // 2 MB (ring 8)
    unsigned short* h2r = (unsigned short*)(ws + off); off += (size_t)8 * BU_ * 2;           // 2 MB
    int* flags1 = (int*)(ws + off); off += (size_t)8 * 128 * 4;   // per-wave flags
    int* flags2 = (int*)(ws + off); off += (size_t)8 * 128 * 4;

    hipMemsetAsync(flags1, 0, (size_t)8 * 128 * 4 * 2, stream);

    int n = B_ * T_ * F_;
    cast_x_kernel<<<(n + 255) / 256, 256, 0, stream>>>(x, xb, n);
    {
        long tot1 = 32L * 2 * 36 * 512;
        pack32_kernel<<<(int)((tot1 + 255) / 256), 256, 0, stream>>>(W1, U1, P1, 36, 64);
        long tot2 = 32L * 2 * 64 * 512;
        pack32_kernel<<<(int)((tot2 + 255) / 256), 256, 0, stream>>>(W2, U2, P2, 64, 512);
    }

    // 256 blocks x 512 thr = 1 block/CU (8 waves): co-residency guaranteed.
    lstm_persist<<<256, 512, 0, stream>>>(xb, P1, P2, b1, b2, h1r, h2r, flags1, flags2);

    dense_kernel<<<B_, 64, 0, stream>>>(h2r + (size_t)((T_ - 1) & 7) * BU_,
                                        Wd, bd, out);
}

// Round 11
// 5488.023 us; speedup vs baseline: 1.0082x; 1.0063x over previous
//
#include <hip/hip_runtime.h>
#include <hip/hip_bf16.h>

#define B_  256
#define T_  256
#define F_  64
#define U_  512
#define NG_ 2048   // 4*U
#define BU_ (B_ * U_)

typedef __attribute__((ext_vector_type(8))) short short8;
typedef __attribute__((ext_vector_type(16))) float floatx16;

__device__ __forceinline__ unsigned short f2bf(float f) {
    union { float f; unsigned int u; } v; v.f = f;
    unsigned int u = v.u;
    return (unsigned short)((u + 0x7FFFu + ((u >> 16) & 1u)) >> 16);
}

__global__ void cast_x_kernel(const float* __restrict__ x,
                              unsigned short* __restrict__ xb, int n) {
    int i = blockIdx.x * blockDim.x + threadIdx.x;
    if (i < n) xb[i] = f2bf(x[i]);
}

// Pack weights into 32x32x16 MFMA B-fragments, per unit-group (16 units -> 64
// block-local gate cols = 2 n32 tiles: [i16|f16] [g16|o16]).
__global__ void pack32_kernel(const float* __restrict__ W, const float* __restrict__ Uw,
                              unsigned short* __restrict__ dst, int KT, int KX) {
    long tid = (long)blockIdx.x * blockDim.x + threadIdx.x;
    long total = 32L * 2 * KT * 512;
    if (tid >= total) return;
    int j    = (int)(tid & 7);
    int lane = (int)((tid >> 3) & 63);
    int p512 = (int)(tid >> 9);
    int kt   = p512 % KT;
    int q    = p512 / KT;
    int nt   = q & 1;
    int ug   = q >> 1;
    int c    = nt * 32 + (lane & 31);
    int srcn = (c >> 4) * U_ + ug * 16 + (c & 15);
    int k    = kt * 16 + (lane >> 5) * 8 + j;
    float v  = (k < KX) ? W[(long)k * NG_ + srcn] : Uw[(long)(k - KX) * NG_ + srcn];
    dst[tid] = f2bf(v);
}

// LLC-coherent 16-B load, NON-atomic: batched issue, latencies overlap.
__device__ __forceinline__ short8 llc_load(const unsigned short* p) {
    short8 r;
    asm volatile("global_load_dwordx4 %0, %1, off sc0 sc1" : "=v"(r) : "v"(p));
    return r;
}
#define VMWAIT(N) asm volatile("s_waitcnt vmcnt(" #N ")" ::: "memory")
__device__ __forceinline__ void dep8(short8& x) { asm volatile("" : "+v"(x)); }

#define MFMA32(a, b, c) __builtin_amdgcn_mfma_f32_32x32x16_bf16(a, b, c, 0, 0, 0)

// 4-wave write-publish sync via LDS seq counters (no block barrier).
__device__ __forceinline__ void seq_publish_wait(int* sq, int wvl, int tgt, int lane) {
    asm volatile("s_waitcnt lgkmcnt(0)" ::: "memory");
    if (lane == 0)
        __hip_atomic_store(&sq[wvl], tgt, __ATOMIC_RELAXED, __HIP_MEMORY_SCOPE_WORKGROUP);
    int gd = 0;
    for (;;) {
        bool ok = true;
        if (lane < 4)
            ok = __hip_atomic_load(&sq[lane], __ATOMIC_RELAXED, __HIP_MEMORY_SCOPE_WORKGROUP) >= tgt;
        if (__ballot(ok) == ~0ull) break;
        if (++gd > (1 << 24)) break;
    }
    __atomic_signal_fence(__ATOMIC_ACQUIRE);
}
__device__ __forceinline__ void seq_wait(int* sq, int tgt, int lane) {
    if (tgt <= 0) return;
    int gd = 0;
    for (;;) {
        bool ok = true;
        if (lane < 4)
            ok = __hip_atomic_load(&sq[lane], __ATOMIC_RELAXED, __HIP_MEMORY_SCOPE_WORKGROUP) >= tgt;
        if (__ballot(ok) == ~0ull) break;
        if (++gd > (1 << 24)) break;
    }
}

// Persistent 2-layer LSTM, layer-per-block wave specialization.
// 512 blocks x 256 thr = 2 blocks/CU (structurally guaranteed: worst-case
// VGPR 2x~240/SIMD <= 512, LDS 2x~35KB <= 160KB). Blocks 0..255 = L1(mo,ug),
// 256..511 = L2(mo,ug). 4 waves k-split per block; weights in VGPRs;
// single-slot LDS reduce with write/read seq counters; per-wave global flags;
// ring depth 8. No __syncthreads and no cache maintenance in the loop.
__global__ __launch_bounds__(256, 2) void lstm_persist(
    const unsigned short* __restrict__ xb,
    const unsigned short* __restrict__ P1,
    const unsigned short* __restrict__ P2,
    const float* __restrict__ b1, const float* __restrict__ b2,
    unsigned short* __restrict__ h1r, unsigned short* __restrict__ h2r,
    int* flags1, int* flags2)
{
    const int bid  = blockIdx.x;
    const int lyr  = bid >> 8;       // 0 = L1, 1 = L2
    const int sub  = bid & 255;
    const int mo   = sub & 7;        // m-octile == XCD family (heuristic)
    const int ug   = sub >> 3;       // 32 unit-groups of 16 units
    const int tid  = threadIdx.x;
    const int wvl  = tid >> 6;       // wave 0..3 (k-split)
    const int lane = tid & 63;
    const int arow = lane & 31;
    const int koff = (lane >> 5) * 8;
    const int row  = mo * 32 + arow;

    int* f1 = flags1 + mo * 128;     // f[ug*4+wvl] = t+1 <=> slice of h[t] at LLC
    int* f2 = flags2 + mo * 128;

    __shared__ float zs[4][2][32][33];   // single-slot partials, 33-pad (33.8 KB)
    __shared__ float bias_s[64];
    __shared__ int   seqw[4], seqr[4];

    if (tid < 4) { seqw[tid] = 0; seqr[tid] = 0; }
    if (tid < 64) {
        const float* bb = lyr ? b2 : b1;
        bias_s[tid] = bb[(tid >> 4) * U_ + ug * 16 + (tid & 15)];
    }
    __syncthreads();   // init only

    const int er = arow;
    const int u0 = wvl * 4 + (lane >> 5) * 2;
    float c_[2] = {0.f, 0.f};

    if (lyr == 0) {
        // ============================ LAYER 1 ============================
        short8 wf0[9], wf1[9];
        {
            const unsigned short* b0 = P1 + (size_t)ug * (2 * 36 * 512);
            #pragma unroll
            for (int i = 0; i < 9; ++i) {
                wf0[i] = *(const short8*)(b0 + (size_t)(0 * 36 + wvl * 9 + i) * 512 + lane * 8);
                wf1[i] = *(const short8*)(b0 + (size_t)(1 * 36 + wvl * 9 + i) * 512 + lane * 8);
            }
        }
        int* myflag = f1 + ug * 4 + wvl;
        const int* pa  = f1 + lane;
        const int* pb  = f1 + 64 + lane;
        const int* pc1 = f2 + lane;        // ring-8 backpressure vs L2 readers
        const int* pc2 = f2 + 64 + lane;

        for (int t = 0; t < T_; ++t) {
            if (t > 0) {
                const int bp = t - 6;
                int gd = 0;
                for (;;) {
                    bool ok = __hip_atomic_load(pa, __ATOMIC_RELAXED, __HIP_MEMORY_SCOPE_AGENT) >= t
                           && __hip_atomic_load(pb, __ATOMIC_RELAXED, __HIP_MEMORY_SCOPE_AGENT) >= t;
                    if (bp > 0)
                        ok = ok && __hip_atomic_load(pc1, __ATOMIC_RELAXED, __HIP_MEMORY_SCOPE_AGENT) >= bp
                                && __hip_atomic_load(pc2, __ATOMIC_RELAXED, __HIP_MEMORY_SCOPE_AGENT) >= bp;
                    if (__ballot(ok) == ~0ull) break;
                    __builtin_amdgcn_s_sleep(1);
                    if (++gd > (1 << 21)) break;
                }
            }
            __atomic_signal_fence(__ATOMIC_ACQUIRE);

            floatx16 acc0, acc1;
            #pragma unroll
            for (int i = 0; i < 16; ++i) { acc0[i] = 0.f; acc1[i] = 0.f; }

            short8 fr[9];
            int nf = 0;
            if (wvl == 0) {
                const unsigned short* xbase = xb + ((size_t)row * T_ + t) * F_;
                #pragma unroll
                for (int i = 0; i < 4; ++i) fr[i] = *(const short8*)(xbase + i * 16 + koff);
                if (t > 0) {
                    const unsigned short* hb = h1r + (size_t)((t - 1) & 7) * BU_ + (size_t)row * U_;
                    #pragma unroll
                    for (int i = 4; i < 9; ++i) fr[i] = llc_load(hb + (i - 4) * 16 + koff);
                    nf = 9;
                } else nf = 4;
            } else if (t > 0) {
                const unsigned short* hb = h1r + (size_t)((t - 1) & 7) * BU_ + (size_t)row * U_
                                           + (wvl * 9 - 4) * 16;
                #pragma unroll
                for (int i = 0; i < 9; ++i) fr[i] = llc_load(hb + i * 16 + koff);
                nf = 9;
            }

            seq_wait(seqr, t, lane);     // previous iter's zs reads done (WAR)

            if (nf == 9) {
                VMWAIT(0);
                #pragma unroll
                for (int i = 0; i < 9; ++i) {
                    dep8(fr[i]);
                    acc0 = MFMA32(fr[i], wf0[i], acc0);
                    acc1 = MFMA32(fr[i], wf1[i], acc1);
                }
            } else if (nf == 4) {
                VMWAIT(0);
                #pragma unroll
                for (int i = 0; i < 4; ++i) {
                    dep8(fr[i]);
                    acc0 = MFMA32(fr[i], wf0[i], acc0);
                    acc1 = MFMA32(fr[i], wf1[i], acc1);
                }
            }

            #pragma unroll
            for (int r = 0; r < 16; ++r) {   // D: col=lane&31, row=(r&3)+8*(r>>2)+4*(lane>>5)
                int rr = (r & 3) + 8 * (r >> 2) + 4 * (lane >> 5);
                zs[wvl][0][rr][arow] = acc0[r];
                zs[wvl][1][rr][arow] = acc1[r];
            }
            seq_publish_wait(seqw, wvl, t + 1, lane);

            {   // epilogue: 2 cells (er, u0..u0+1)
                unsigned int pk = 0;
                #pragma unroll
                for (int j = 0; j < 2; ++j) {
                    int u = u0 + j;
                    float zi = bias_s[u], zf = bias_s[16 + u], zg = bias_s[32 + u], zo = bias_s[48 + u];
                    #pragma unroll
                    for (int ww = 0; ww < 4; ++ww) {
                        zi += zs[ww][0][er][u];
                        zf += zs[ww][0][er][16 + u];
                        zg += zs[ww][1][er][u];
                        zo += zs[ww][1][er][16 + u];
                    }
                    float si = 1.f / (1.f + __expf(-zi));
                    float sf = 1.f / (1.f + __expf(-zf));
                    float so = 1.f / (1.f + __expf(-zo));
                    float gg = zg > 0.f ? zg : 0.f;
                    float cn = sf * c_[j] + si * gg;
                    c_[j] = cn;
                    float hn = so * (cn > 0.f ? cn : 0.f);
                    pk |= ((unsigned int)f2bf(hn)) << (16 * j);
                }
                if (lane == 0)
                    __hip_atomic_store(&seqr[wvl], t + 1, __ATOMIC_RELAXED, __HIP_MEMORY_SCOPE_WORKGROUP);
                unsigned int* hp = (unsigned int*)(h1r + (size_t)(t & 7) * BU_
                                   + (size_t)(mo * 32 + er) * U_ + ug * 16 + u0);
                __hip_atomic_store(hp, pk, __ATOMIC_RELAXED, __HIP_MEMORY_SCOPE_AGENT);
            }
            VMWAIT(0);                               // own h-store acked at LLC
            __atomic_signal_fence(__ATOMIC_RELEASE);
            if (lane == 0)
                __hip_atomic_store(myflag, t + 1, __ATOMIC_RELAXED, __HIP_MEMORY_SCOPE_AGENT);
        }
    } else {
        // ============================ LAYER 2 ============================
        short8 wf0[16], wf1[16];     // wvl 0,1 = W2*h1[t]; wvl 2,3 = U2*h2[t-1]
        {
            const unsigned short* b0 = P2 + (size_t)ug * (2 * 64 * 512);
            #pragma unroll
            for (int i = 0; i < 16; ++i) {
                int kt = wvl * 16 + i;
                wf0[i] = *(const short8*)(b0 + (size_t)(0 * 64 + kt) * 512 + lane * 8);
                wf1[i] = *(const short8*)(b0 + (size_t)(1 * 64 + kt) * 512 + lane * 8);
            }
        }
        int* myflag = f2 + ug * 4 + wvl;
        const int* pa = (wvl < 2) ? (f1 + lane) : (f2 + lane);
        const int* pb = (wvl < 2) ? (f1 + 64 + lane) : (f2 + 64 + lane);

        for (int t = 0; t < T_; ++t) {
            const int tgt = (wvl < 2) ? (t + 1) : t;
            if (tgt > 0) {
                int gd = 0;
                for (;;) {
                    bool ok = __hip_atomic_load(pa, __ATOMIC_RELAXED, __HIP_MEMORY_SCOPE_AGENT) >= tgt
                           && __hip_atomic_load(pb, __ATOMIC_RELAXED, __HIP_MEMORY_SCOPE_AGENT) >= tgt;
                    if (__ballot(ok) == ~0ull) break;
                    __builtin_amdgcn_s_sleep(1);
                    if (++gd > (1 << 21)) break;
                }
            }
            __atomic_signal_fence(__ATOMIC_ACQUIRE);

            floatx16 acc0, acc1;
            #pragma unroll
            for (int i = 0; i < 16; ++i) { acc0[i] = 0.f; acc1[i] = 0.f; }

            bool have = false;
            short8 fr[16];
            if (wvl < 2) {
                const unsigned short* hb = h1r + (size_t)(t & 7) * BU_ + (size_t)row * U_
                                           + wvl * 256;
                #pragma unroll
                for (int i = 0; i < 16; ++i) fr[i] = llc_load(hb + i * 16 + koff);
                have = true;
            } else if (t > 0) {
                const unsigned short* hb = h2r + (size_t)((t - 1) & 7) * BU_ + (size_t)row * U_
                                           + (wvl - 2) * 256;
                #pragma unroll
                for (int i = 0; i < 16; ++i) fr[i] = llc_load(hb + i * 16 + koff);
                have = true;
            }

            seq_wait(seqr, t, lane);

            if (have) {
                VMWAIT(8);
                #pragma unroll
                for (int i = 0; i < 8; ++i) {
                    dep8(fr[i]);
                    acc0 = MFMA32(fr[i], wf0[i], acc0);
                    acc1 = MFMA32(fr[i], wf1[i], acc1);
                }
                VMWAIT(0);
                #pragma unroll
                for (int i = 8; i < 16; ++i) {
                    dep8(fr[i]);
                    acc0 = MFMA32(fr[i], wf0[i], acc0);
                    acc1 = MFMA32(fr[i], wf1[i], acc1);
                }
            }

            #pragma unroll
            for (int r = 0; r < 16; ++r) {
                int rr = (r & 3) + 8 * (r >> 2) + 4 * (lane >> 5);
                zs[wvl][0][rr][arow] = acc0[r];
                zs[wvl][1][rr][arow] = acc1[r];
            }
            seq_publish_wait(seqw, wvl, t + 1, lane);

            {
                unsigned int pk = 0;
                #pragma unroll
                for (int j = 0; j < 2; ++j) {
                    int u = u0 + j;
                    float zi = bias_s[u], zf = bias_s[16 + u], zg = bias_s[32 + u], zo = bias_s[48 + u];
                    #pragma unroll
                    for (int ww = 0; ww < 4; ++ww) {
                        zi += zs[ww][0][er][u];
                        zf += zs[ww][0][er][16 + u];
                        zg += zs[ww][1][er][u];
                        zo += zs[ww][1][er][16 + u];
                    }
                    float si = 1.f / (1.f + __expf(-zi));
                    float sf = 1.f / (1.f + __expf(-zf));
                    float so = 1.f / (1.f + __expf(-zo));
                    float gg = zg > 0.f ? zg : 0.f;
                    float cn = sf * c_[j] + si * gg;
                    c_[j] = cn;
                    float hn = so * (cn > 0.f ? cn : 0.f);
                    pk |= ((unsigned int)f2bf(hn)) << (16 * j);
                }
                if (lane == 0)
                    __hip_atomic_store(&seqr[wvl], t + 1, __ATOMIC_RELAXED, __HIP_MEMORY_SCOPE_WORKGROUP);
                unsigned int* hp = (unsigned int*)(h2r + (size_t)(t & 7) * BU_
                                   + (size_t)(mo * 32 + er) * U_ + ug * 16 + u0);
                __hip_atomic_store(hp, pk, __ATOMIC_RELAXED, __HIP_MEMORY_SCOPE_AGENT);
            }
            VMWAIT(0);
            __atomic_signal_fence(__ATOMIC_RELEASE);
            if (lane == 0)
                __hip_atomic_store(myflag, t + 1, __ATOMIC_RELAXED, __HIP_MEMORY_SCOPE_AGENT);
        }
    }
}

__global__ void dense_kernel(const unsigned short* __restrict__ h2,
                             const float* __restrict__ Wd,
                             const float* __restrict__ bd,
                             float* __restrict__ out) {
    int b = blockIdx.x;
    int lane = threadIdx.x;                  // 64 lanes
    const unsigned short* hp = h2 + (long)b * U_ + lane * 8;
    float sum = 0.f;
    #pragma unroll
    for (int j = 0; j < 8; ++j) {
        union { unsigned int u; float f; } v; v.u = ((unsigned int)hp[j]) << 16;
        sum += v.f * Wd[lane * 8 + j];
    }
    #pragma unroll
    for (int off = 32; off; off >>= 1) sum += __shfl_down(sum, off);
    if (lane == 0) out[b] = 1.f / (1.f + __expf(-(sum + bd[0])));
}

extern "C" void kernel_launch(void* const* d_in, const int* in_sizes, int n_in,
                              void* d_out, int out_size, void* d_ws, size_t ws_size,
                              hipStream_t stream) {
    const float* x  = (const float*)d_in[0];
    const float* W1 = (const float*)d_in[1];
    const float* U1 = (const float*)d_in[2];
    const float* b1 = (const float*)d_in[3];
    const float* W2 = (const float*)d_in[4];
    const float* U2 = (const float*)d_in[5];
    const float* b2 = (const float*)d_in[6];
    const float* Wd = (const float*)d_in[7];
    const float* bd = (const float*)d_in[8];
    float* out = (float*)d_out;

    char* ws = (char*)d_ws;
    size_t off = 0;
    unsigned short* xb  = (unsigned short*)(ws + off); off += (size_t)B_ * T_ * F_ * 2;      // 8.39 MB
    unsigned short* P1  = (unsigned short*)(ws + off); off += (size_t)32 * 2 * 36 * 512 * 2; // 2.36 MB
    unsigned short* P2  = (unsigned short*)(ws + off); off += (size_t)32 * 2 * 64 * 512 * 2; // 4.19 MB
    unsigned short* h1r = (unsigned short*)(ws + off); off += (size_t)8 * BU_ * 2;           // 2 MB (ring 8)
    unsigned short* h2r = (unsigned short*)(ws + off); off += (size_t)8 * BU_ * 2;           // 2 MB
    int* flags1 = (int*)(ws + off); off += (size_t)8 * 128 * 4;   // per-wave flags
    int* flags2 = (int*)(ws + off); off += (size_t)8 * 128 * 4;

    hipMemsetAsync(flags1, 0, (size_t)8 * 128 * 4 * 2, stream);

    int n = B_ * T_ * F_;
    cast_x_kernel<<<(n + 255) / 256, 256, 0, stream>>>(x, xb, n);
    {
        long tot1 = 32L * 2 * 36 * 512;
        pack32_kernel<<<(int)((tot1 + 255) / 256), 256, 0, stream>>>(W1, U1, P1, 36, 64);
        long tot2 = 32L * 2 * 64 * 512;
        pack32_kernel<<<(int)((tot2 + 255) / 256), 256, 0, stream>>>(W2, U2, P2, 64, 512);
    }

    // 512 blocks x 256 thr = 2 blocks/CU: full co-residency guaranteed
    // (worst pairing 2xL2: VGPR 2x~240 <= 512/SIMD, LDS 2x~35KB <= 160KB).
    lstm_persist<<<512, 256, 0, stream>>>(xb, P1, P2, b1, b2, h1r, h2r, flags1, flags2);

    dense_kernel<<<B_, 64, 0, stream>>>(h2r + (size_t)((T_ - 1) & 7) * BU_,
                                        Wd, bd, out);
}